// Round 1
// baseline (99.026 us; speedup 1.0000x reference)
//
#include <hip/hip_runtime.h>
#include <hip/hip_bf16.h>

// DetectionLoss: focal cls loss + GIoU box loss (EfficientDet-style), MI355X.
//
// Input order (setup_inputs dict order):
//   for level i in 0..4: d_in[4i+0]=cls_out (B,810,H,W) f32
//                        d_in[4i+1]=box_out (B,36,H,W)  f32
//                        d_in[4i+2]=cls_tgt (B,H,W,9)   i32
//                        d_in[4i+3]=box_tgt (B,H,W,36)  f32
//   d_in[20]=num_positives (8,) f32 ; d_in[21]=anchors (49104,4) f32
// Output: 3 f32 [total, cls_loss, box_loss]

#define CLS_GRID 2048
#define BOX_GRID 512

struct ClsPtrs { const float* co[5]; const int* ct[5]; };
struct BoxPtrs { const float* bo[5]; const float* bt[5]; };

// per-level cls element counts (B*810*HW*HW), cumulative:
//  l0: 26,542,080 -> 26,542,080
//  l1:  6,635,520 -> 33,177,600
//  l2:  1,658,880 -> 34,836,480
//  l3:    414,720 -> 35,251,200
//  l4:    103,680 -> 35,354,880
#define CLS_TOTAL 35354880
#define NGROUPS   (CLS_TOTAL / 4)

// per-level anchor counts (9*HW*HW), cumulative within N=49104:
//  36864, 46080, 48384, 48960, 49104
#define NANCH 49104
#define BN    (8 * NANCH)

__device__ __forceinline__ float block_reduce(float v, float* sred) {
    for (int off = 32; off; off >>= 1) v += __shfl_down(v, off, 64);
    const int lane = threadIdx.x & 63, wv = threadIdx.x >> 6;
    if (lane == 0) sred[wv] = v;
    __syncthreads();
    float r = 0.f;
    if (threadIdx.x == 0) r = sred[0] + sred[1] + sred[2] + sred[3];
    __syncthreads();
    return r;
}

__global__ __launch_bounds__(256) void cls_kernel(ClsPtrs P, float* partial) {
    const int tid = blockIdx.x * blockDim.x + threadIdx.x;
    const int nth = gridDim.x * blockDim.x;
    float acc = 0.f;

    for (int g = tid; g < NGROUPS; g += nth) {
        const int e = g << 2;
        const float* co; const int* ct; int lw, local;
        if (e < 26542080)      { co = P.co[0]; ct = P.ct[0]; lw = 6; local = e; }
        else if (e < 33177600) { co = P.co[1]; ct = P.ct[1]; lw = 5; local = e - 26542080; }
        else if (e < 34836480) { co = P.co[2]; ct = P.ct[2]; lw = 4; local = e - 33177600; }
        else if (e < 35251200) { co = P.co[3]; ct = P.ct[3]; lw = 3; local = e - 34836480; }
        else                   { co = P.co[4]; ct = P.ct[4]; lw = 2; local = e - 35251200; }
        const int plane = 1 << (2 * lw);          // H*W
        const int hw    = local & (plane - 1);    // h*W + w
        const int bc    = local >> (2 * lw);      // b*810 + c
        const int b     = bc / 810;
        const int c     = bc - b * 810;
        const int a     = c / 90;
        const int k     = c - a * 90;
        const int ctbase = (b * plane + hw) * 9 + a;

        const float4 v = *reinterpret_cast<const float4*>(co + local);
        const float xs[4] = { v.x, v.y, v.z, v.w };

        #pragma unroll
        for (int j = 0; j < 4; ++j) {
            const int   ctv = ct[ctbase + 9 * j];
            const float x   = xs[j];
            const bool  tgt = (ctv == k);            // implies ctv >= 0
            const float t   = tgt ? 1.f : 0.f;
            const float keep = (ctv != -2) ? 1.f : 0.f;
            const float ax  = fabsf(x);
            const float e1  = __expf(-ax);           // exp(-|x|), in (0,1]
            const float lg  = __logf(1.f + e1);      // log1p(exp(-|x|))
            const float bce = fmaxf(x, 0.f) - x * t + lg;
            const float pp  = __builtin_amdgcn_rcpf(1.f + e1);  // sigmoid(|x|)
            const float qq  = e1 * pp;                          // 1 - sigmoid(|x|)
            const bool  pos = (x >= 0.f);
            const float sig = pos ? pp : qq;                    // sigmoid(x)
            const float om  = tgt ? (1.f - sig) : sig;          // 1 - p_t
            const float mod = om * sqrtf(om);                   // om^1.5
            const float af  = tgt ? 0.25f : 0.75f;
            acc += keep * af * mod * bce;
        }
    }

    __shared__ float sred[4];
    const float r = block_reduce(acc, sred);
    if (threadIdx.x == 0) partial[blockIdx.x] = r;
}

__global__ __launch_bounds__(256) void box_kernel(BoxPtrs P, const float* __restrict__ anchors,
                                                 float* bpart, float* mpart) {
    const int tid = blockIdx.x * blockDim.x + threadIdx.x;
    const int nth = gridDim.x * blockDim.x;
    float accL = 0.f, accM = 0.f;

    for (int idx = tid; idx < BN; idx += nth) {
        const int b = idx / NANCH;
        const int n = idx - b * NANCH;
        const float* bo; const float* bt; int lw, nl;
        if (n < 36864)      { bo = P.bo[0]; bt = P.bt[0]; lw = 6; nl = n; }
        else if (n < 46080) { bo = P.bo[1]; bt = P.bt[1]; lw = 5; nl = n - 36864; }
        else if (n < 48384) { bo = P.bo[2]; bt = P.bt[2]; lw = 4; nl = n - 46080; }
        else if (n < 48960) { bo = P.bo[3]; bt = P.bt[3]; lw = 3; nl = n - 48384; }
        else                { bo = P.bo[4]; bt = P.bt[4]; lw = 2; nl = n - 48960; }
        const int a  = nl % 9;
        const int hw = nl / 9;
        const int plane = 1 << (2 * lw);

        const float4 r = *reinterpret_cast<const float4*>(bt + (((b * plane + hw) * 9 + a) << 2));
        if (r.x != 0.f && r.y != 0.f && r.z != 0.f && r.w != 0.f) {
            accM += 1.f;
            const float* base = bo + (b * 36 + a * 4) * plane + hw;
            const float o0 = base[0], o1 = base[plane], o2 = base[2 * plane], o3 = base[3 * plane];
            const float4 an = *reinterpret_cast<const float4*>(anchors + 4 * n);
            const float ha = an.z - an.x, wa = an.w - an.y;
            const float yca = (an.x + an.z) * 0.5f, xca = (an.y + an.w) * 0.5f;
            // decode target (ty,tx,th,tw = r.x,r.y,r.z,r.w)
            const float th_ = __expf(r.z) * ha, tw_ = __expf(r.w) * wa;
            const float tyc = r.x * ha + yca,  txc = r.y * wa + xca;
            const float ty1 = tyc - th_ * 0.5f, tx1 = txc - tw_ * 0.5f;
            const float ty2 = tyc + th_ * 0.5f, tx2 = txc + tw_ * 0.5f;
            // decode output
            const float oh_ = __expf(o2) * ha, ow_ = __expf(o3) * wa;
            const float oyc = o0 * ha + yca,  oxc = o1 * wa + xca;
            const float oy1 = oyc - oh_ * 0.5f, ox1 = oxc - ow_ * 0.5f;
            const float oy2 = oyc + oh_ * 0.5f, ox2 = oxc + ow_ * 0.5f;

            const float Ag = (tx2 - tx1) * (ty2 - ty1);
            const float Ap = (ox2 - ox1) * (oy2 - oy1);
            const float yi1 = fmaxf(ty1, oy1), xi1 = fmaxf(tx1, ox1);
            const float yi2 = fminf(ty2, oy2), xi2 = fminf(tx2, ox2);
            const float I  = (xi2 > xi1 && yi2 > yi1) ? (xi2 - xi1) * (yi2 - yi1) : 0.f;
            const float U  = Ap + Ag - I;
            const float iou = I / (U + 1e-7f);
            const float yo1 = fminf(ty1, oy1), xo1 = fminf(tx1, ox1);
            const float yo2 = fmaxf(ty2, oy2), xo2 = fmaxf(tx2, ox2);
            const float Ac = (xo2 - xo1) * (yo2 - yo1);
            const float pen = (Ac - U) / (Ac + 1e-7f);
            accL += 1.f - iou + pen;
        }
    }

    __shared__ float sred[4];
    const float rl = block_reduce(accL, sred);
    if (threadIdx.x == 0) bpart[blockIdx.x] = rl;
    __syncthreads();
    const float rm = block_reduce(accM, sred);
    if (threadIdx.x == 0) mpart[blockIdx.x] = rm;
}

__global__ __launch_bounds__(256) void finalize_kernel(const float* __restrict__ ws,
                                                       const float* __restrict__ npos,
                                                       float* __restrict__ out) {
    float c = 0.f, bx = 0.f, mk = 0.f;
    for (int i = threadIdx.x; i < CLS_GRID; i += 256) c += ws[i];
    for (int i = threadIdx.x; i < BOX_GRID; i += 256) {
        bx += ws[CLS_GRID + i];
        mk += ws[CLS_GRID + BOX_GRID + i];
    }
    __shared__ float sred[4];
    const float C  = block_reduce(c,  sred);
    __syncthreads();
    const float Bx = block_reduce(bx, sred);
    __syncthreads();
    const float Mk = block_reduce(mk, sred);
    if (threadIdx.x == 0) {
        float nps = 1.f;
        #pragma unroll
        for (int i = 0; i < 8; ++i) nps += npos[i];
        const float cls = C / nps;
        const float box = Bx / Mk;
        out[0] = cls + 50.f * box;
        out[1] = cls;
        out[2] = box;
    }
}

extern "C" void kernel_launch(void* const* d_in, const int* in_sizes, int n_in,
                              void* d_out, int out_size, void* d_ws, size_t ws_size,
                              hipStream_t stream) {
    ClsPtrs cp; BoxPtrs bp;
    for (int i = 0; i < 5; ++i) {
        cp.co[i] = (const float*)d_in[i * 4 + 0];
        bp.bo[i] = (const float*)d_in[i * 4 + 1];
        cp.ct[i] = (const int*)  d_in[i * 4 + 2];
        bp.bt[i] = (const float*)d_in[i * 4 + 3];
    }
    const float* npos    = (const float*)d_in[20];
    const float* anchors = (const float*)d_in[21];
    float* ws = (float*)d_ws;

    cls_kernel<<<CLS_GRID, 256, 0, stream>>>(cp, ws);
    box_kernel<<<BOX_GRID, 256, 0, stream>>>(bp, anchors, ws + CLS_GRID, ws + CLS_GRID + BOX_GRID);
    finalize_kernel<<<1, 256, 0, stream>>>(ws, npos, (float*)d_out);
}

// Round 2
// 62.894 us; speedup vs baseline: 1.5745x; 1.5745x over previous
//
#include <hip/hip_runtime.h>
#include <hip/hip_bf16.h>

// DetectionLoss: focal cls loss + GIoU box loss (EfficientDet-style), MI355X.
//
// Input order (setup_inputs dict order):
//   for level i in 0..4: d_in[4i+0]=cls_out (B,810,H,W) f32
//                        d_in[4i+1]=box_out (B,36,H,W)  f32
//                        d_in[4i+2]=cls_tgt (B,H,W,9)   i32
//                        d_in[4i+3]=box_tgt (B,H,W,36)  f32
//   d_in[20]=num_positives (8,) f32 ; d_in[21]=anchors (49104,4) f32
// Output: 3 f32 [total, cls_loss, box_loss]
//
// cls kernel structure (round 1): thread <-> (level,b,a,hw-quad,ksplit).
// Loop over 15 classes with coalesced float4 logit loads (stride=plane);
// the scattered stride-36B cls_tgt loads happen once per task (4 loads per
// 60 logit elements) instead of once per element-quad (90x reduction).

#define BOX_GRID 512

struct ClsPtrs { const float* co[5]; const int* ct[5]; };
struct BoxPtrs { const float* bo[5]; const float* bt[5]; };

// per-level quad counts (B*9*plane/4), cumulative:
//  l0: 73728 -> 73728
//  l1: 18432 -> 92160
//  l2:  4608 -> 96768
//  l3:  1152 -> 97920
//  l4:   288 -> 98208
#define NQUADS 98208
#define KSPLIT 6
#define KPER   15              // 90 / KSPLIT
#define NTASKS (NQUADS * KSPLIT)      // 589248
#define CLS_GRID ((NTASKS + 255) / 256)  // 2302

// anchors: per-level counts (9*HW*HW), cumulative within N=49104:
//  36864, 46080, 48384, 48960, 49104
#define NANCH 49104
#define BN    (8 * NANCH)

__device__ __forceinline__ float block_reduce(float v, float* sred) {
    for (int off = 32; off; off >>= 1) v += __shfl_down(v, off, 64);
    const int lane = threadIdx.x & 63, wv = threadIdx.x >> 6;
    if (lane == 0) sred[wv] = v;
    __syncthreads();
    float r = 0.f;
    if (threadIdx.x == 0) r = sred[0] + sred[1] + sred[2] + sred[3];
    __syncthreads();
    return r;
}

__device__ __forceinline__ float focal(float x, bool tgt, float a25, float a75) {
    const float ax  = fabsf(x);
    const float e1  = __expf(-ax);                      // exp(-|x|), (0,1]
    const float lg  = __logf(1.f + e1);                 // log1p(exp(-|x|))
    const float bce = fmaxf(x, 0.f) + lg - (tgt ? x : 0.f);
    const float pp  = __builtin_amdgcn_rcpf(1.f + e1);  // sigmoid(|x|)
    const float sig = (x >= 0.f) ? pp : e1 * pp;        // sigmoid(x)
    const float om  = tgt ? (1.f - sig) : sig;          // 1 - p_t
    const float mod = om * sqrtf(om);                   // om^1.5
    const float af  = tgt ? a25 : a75;                  // 0 if masked (ct==-2)
    return af * mod * bce;
}

__global__ __launch_bounds__(256) void cls_kernel(ClsPtrs P, float* partial) {
    const int t = blockIdx.x * 256 + threadIdx.x;
    float acc = 0.f;

    if (t < NTASKS) {
        const int s = t / NQUADS;          // which k-chunk, 0..5
        const int q = t - s * NQUADS;      // quad id (consecutive across lanes)

        const float* co; const int* ct; int p4s, ql;
        if (q < 73728)      { co = P.co[0]; ct = P.ct[0]; p4s = 10; ql = q; }
        else if (q < 92160) { co = P.co[1]; ct = P.ct[1]; p4s = 8;  ql = q - 73728; }
        else if (q < 96768) { co = P.co[2]; ct = P.ct[2]; p4s = 6;  ql = q - 92160; }
        else if (q < 97920) { co = P.co[3]; ct = P.ct[3]; p4s = 4;  ql = q - 96768; }
        else                { co = P.co[4]; ct = P.ct[4]; p4s = 2;  ql = q - 97920; }

        const int plane4 = 1 << p4s;
        const int plane  = plane4 << 2;        // H*W
        const int hwq = ql & (plane4 - 1);
        const int ba  = ql >> p4s;             // b*9 + a
        const int b   = ba / 9;
        const int a   = ba - 9 * b;
        const int hw0 = hwq << 2;

        const int ctbase = (b * plane + hw0) * 9 + a;
        const int c0 = ct[ctbase], c1 = ct[ctbase + 9], c2 = ct[ctbase + 18], c3 = ct[ctbase + 27];
        const float a25x = (c0 != -2) ? 0.25f : 0.f, a75x = (c0 != -2) ? 0.75f : 0.f;
        const float a25y = (c1 != -2) ? 0.25f : 0.f, a75y = (c1 != -2) ? 0.75f : 0.f;
        const float a25z = (c2 != -2) ? 0.25f : 0.f, a75z = (c2 != -2) ? 0.75f : 0.f;
        const float a25w = (c3 != -2) ? 0.25f : 0.f, a75w = (c3 != -2) ? 0.75f : 0.f;

        const int k0 = s * KPER;
        const float* cptr = co + (b * 810 + a * 90 + k0) * plane + hw0;

        #pragma unroll 5
        for (int kk = 0; kk < KPER; ++kk) {
            const int k = k0 + kk;
            const float4 v = *reinterpret_cast<const float4*>(cptr);
            cptr += plane;
            acc += focal(v.x, c0 == k, a25x, a75x);
            acc += focal(v.y, c1 == k, a25y, a75y);
            acc += focal(v.z, c2 == k, a25z, a75z);
            acc += focal(v.w, c3 == k, a25w, a75w);
        }
    }

    __shared__ float sred[4];
    const float r = block_reduce(acc, sred);
    if (threadIdx.x == 0) partial[blockIdx.x] = r;
}

__global__ __launch_bounds__(256) void box_kernel(BoxPtrs P, const float* __restrict__ anchors,
                                                 float* bpart, float* mpart) {
    const int tid = blockIdx.x * blockDim.x + threadIdx.x;
    const int nth = gridDim.x * blockDim.x;
    float accL = 0.f, accM = 0.f;

    for (int idx = tid; idx < BN; idx += nth) {
        const int b = idx / NANCH;
        const int n = idx - b * NANCH;
        const float* bo; const float* bt; int lw, nl;
        if (n < 36864)      { bo = P.bo[0]; bt = P.bt[0]; lw = 6; nl = n; }
        else if (n < 46080) { bo = P.bo[1]; bt = P.bt[1]; lw = 5; nl = n - 36864; }
        else if (n < 48384) { bo = P.bo[2]; bt = P.bt[2]; lw = 4; nl = n - 46080; }
        else if (n < 48960) { bo = P.bo[3]; bt = P.bt[3]; lw = 3; nl = n - 48384; }
        else                { bo = P.bo[4]; bt = P.bt[4]; lw = 2; nl = n - 48960; }
        const int a  = nl % 9;
        const int hw = nl / 9;
        const int plane = 1 << (2 * lw);

        const float4 r = *reinterpret_cast<const float4*>(bt + (((b * plane + hw) * 9 + a) << 2));
        if (r.x != 0.f && r.y != 0.f && r.z != 0.f && r.w != 0.f) {
            accM += 1.f;
            const float* base = bo + (b * 36 + a * 4) * plane + hw;
            const float o0 = base[0], o1 = base[plane], o2 = base[2 * plane], o3 = base[3 * plane];
            const float4 an = *reinterpret_cast<const float4*>(anchors + 4 * n);
            const float ha = an.z - an.x, wa = an.w - an.y;
            const float yca = (an.x + an.z) * 0.5f, xca = (an.y + an.w) * 0.5f;
            const float th_ = __expf(r.z) * ha, tw_ = __expf(r.w) * wa;
            const float tyc = r.x * ha + yca,  txc = r.y * wa + xca;
            const float ty1 = tyc - th_ * 0.5f, tx1 = txc - tw_ * 0.5f;
            const float ty2 = tyc + th_ * 0.5f, tx2 = txc + tw_ * 0.5f;
            const float oh_ = __expf(o2) * ha, ow_ = __expf(o3) * wa;
            const float oyc = o0 * ha + yca,  oxc = o1 * wa + xca;
            const float oy1 = oyc - oh_ * 0.5f, ox1 = oxc - ow_ * 0.5f;
            const float oy2 = oyc + oh_ * 0.5f, ox2 = oxc + ow_ * 0.5f;

            const float Ag = (tx2 - tx1) * (ty2 - ty1);
            const float Ap = (ox2 - ox1) * (oy2 - oy1);
            const float yi1 = fmaxf(ty1, oy1), xi1 = fmaxf(tx1, ox1);
            const float yi2 = fminf(ty2, oy2), xi2 = fminf(tx2, ox2);
            const float I  = (xi2 > xi1 && yi2 > yi1) ? (xi2 - xi1) * (yi2 - yi1) : 0.f;
            const float U  = Ap + Ag - I;
            const float iou = I / (U + 1e-7f);
            const float yo1 = fminf(ty1, oy1), xo1 = fminf(tx1, ox1);
            const float yo2 = fmaxf(ty2, oy2), xo2 = fmaxf(tx2, ox2);
            const float Ac = (xo2 - xo1) * (yo2 - yo1);
            const float pen = (Ac - U) / (Ac + 1e-7f);
            accL += 1.f - iou + pen;
        }
    }

    __shared__ float sred[4];
    const float rl = block_reduce(accL, sred);
    if (threadIdx.x == 0) bpart[blockIdx.x] = rl;
    __syncthreads();
    const float rm = block_reduce(accM, sred);
    if (threadIdx.x == 0) mpart[blockIdx.x] = rm;
}

__global__ __launch_bounds__(256) void finalize_kernel(const float* __restrict__ ws,
                                                       const float* __restrict__ npos,
                                                       float* __restrict__ out) {
    float c = 0.f, bx = 0.f, mk = 0.f;
    for (int i = threadIdx.x; i < CLS_GRID; i += 256) c += ws[i];
    for (int i = threadIdx.x; i < BOX_GRID; i += 256) {
        bx += ws[CLS_GRID + i];
        mk += ws[CLS_GRID + BOX_GRID + i];
    }
    __shared__ float sred[4];
    const float C  = block_reduce(c,  sred);
    __syncthreads();
    const float Bx = block_reduce(bx, sred);
    __syncthreads();
    const float Mk = block_reduce(mk, sred);
    if (threadIdx.x == 0) {
        float nps = 1.f;
        #pragma unroll
        for (int i = 0; i < 8; ++i) nps += npos[i];
        const float cls = C / nps;
        const float box = Bx / Mk;
        out[0] = cls + 50.f * box;
        out[1] = cls;
        out[2] = box;
    }
}

extern "C" void kernel_launch(void* const* d_in, const int* in_sizes, int n_in,
                              void* d_out, int out_size, void* d_ws, size_t ws_size,
                              hipStream_t stream) {
    ClsPtrs cp; BoxPtrs bp;
    for (int i = 0; i < 5; ++i) {
        cp.co[i] = (const float*)d_in[i * 4 + 0];
        bp.bo[i] = (const float*)d_in[i * 4 + 1];
        cp.ct[i] = (const int*)  d_in[i * 4 + 2];
        bp.bt[i] = (const float*)d_in[i * 4 + 3];
    }
    const float* npos    = (const float*)d_in[20];
    const float* anchors = (const float*)d_in[21];
    float* ws = (float*)d_ws;

    cls_kernel<<<CLS_GRID, 256, 0, stream>>>(cp, ws);
    box_kernel<<<BOX_GRID, 256, 0, stream>>>(bp, anchors, ws + CLS_GRID, ws + CLS_GRID + BOX_GRID);
    finalize_kernel<<<1, 256, 0, stream>>>(ws, npos, (float*)d_out);
}

// Round 3
// 40.925 us; speedup vs baseline: 2.4197x; 1.5368x over previous
//
#include <hip/hip_runtime.h>
#include <hip/hip_bf16.h>

// DetectionLoss: focal cls loss + GIoU box loss (EfficientDet-style), MI355X.
//
// Input order (setup_inputs dict order):
//   for level i in 0..4: d_in[4i+0]=cls_out (B,810,H,W) f32
//                        d_in[4i+1]=box_out (B,36,H,W)  f32
//                        d_in[4i+2]=cls_tgt (B,H,W,9)   i32
//                        d_in[4i+3]=box_tgt (B,H,W,36)  f32
//   d_in[20]=num_positives (8,) f32 ; d_in[21]=anchors (49104,4) f32
// Output: 3 f32 [total, cls_loss, box_loss]
//
// cls kernel (round 2): 3-transcendental focal via log-space:
//   y = tgt ? -x : x ; loss = af * sigmoid(y)^1.5 * softplus(y)
//   t0 = -|y|*log2e; e1 = exp2(t0); u = 1+e1; lg = log2(u)
//   softplus = max(y,0) + lg*ln2 ; log2(sig) = (y<0 ? t0-lg : -lg)
//   sig^1.5 = exp2(1.5*log2(sig))   -- no rcp, no sqrt fixup sequence.

#define BOX_GRID 512

struct ClsPtrs { const float* co[5]; const int* ct[5]; };
struct BoxPtrs { const float* bo[5]; const float* bt[5]; };

#define NQUADS 98208
#define KSPLIT 6
#define KPER   15                         // 90 / KSPLIT
#define NTASKS (NQUADS * KSPLIT)          // 589248
#define CLS_GRID ((NTASKS + 255) / 256)   // 2302

#define NANCH 49104
#define BN    (8 * NANCH)

#define LOG2E 1.44269504f
#define LN2   0.69314718f

__device__ __forceinline__ float block_reduce(float v, float* sred) {
    for (int off = 32; off; off >>= 1) v += __shfl_down(v, off, 64);
    const int lane = threadIdx.x & 63, wv = threadIdx.x >> 6;
    if (lane == 0) sred[wv] = v;
    __syncthreads();
    float r = 0.f;
    if (threadIdx.x == 0) r = sred[0] + sred[1] + sred[2] + sred[3];
    __syncthreads();
    return r;
}

// af = 0.25/0.75 (already masked by keep); tgt flips the logit sign.
__device__ __forceinline__ float focal3(float x, bool tgt, float a25k, float a75k) {
    const float y  = tgt ? -x : x;
    const float t0 = -LOG2E * fabsf(y);                    // log2(exp(-|y|))
    const float e1 = __builtin_amdgcn_exp2f(t0);
    const float u  = 1.f + e1;
    const float lg = __builtin_amdgcn_logf(u);             // log2(u)
    const float sp = fmaf(lg, LN2, fmaxf(y, 0.f));         // softplus(y)
    const float lz = (y < 0.f) ? (t0 - lg) : -lg;          // log2(sigmoid(y))
    const float zp = __builtin_amdgcn_exp2f(1.5f * lz);    // sigmoid(y)^1.5
    const float af = tgt ? a25k : a75k;
    return af * zp * sp;
}

__global__ __launch_bounds__(256) void cls_kernel(ClsPtrs P, float* partial) {
    const int t = blockIdx.x * 256 + threadIdx.x;
    float ax_ = 0.f, ay_ = 0.f, az_ = 0.f, aw_ = 0.f;   // 4 independent chains

    if (t < NTASKS) {
        const int s = t / NQUADS;          // which k-chunk, 0..5
        const int q = t - s * NQUADS;      // quad id (consecutive across lanes)

        const float* co; const int* ct; int p4s, ql;
        if (q < 73728)      { co = P.co[0]; ct = P.ct[0]; p4s = 10; ql = q; }
        else if (q < 92160) { co = P.co[1]; ct = P.ct[1]; p4s = 8;  ql = q - 73728; }
        else if (q < 96768) { co = P.co[2]; ct = P.ct[2]; p4s = 6;  ql = q - 92160; }
        else if (q < 97920) { co = P.co[3]; ct = P.ct[3]; p4s = 4;  ql = q - 96768; }
        else                { co = P.co[4]; ct = P.ct[4]; p4s = 2;  ql = q - 97920; }

        const int plane4 = 1 << p4s;
        const int plane  = plane4 << 2;        // H*W
        const int hwq = ql & (plane4 - 1);
        const int ba  = ql >> p4s;             // b*9 + a
        const int b   = ba / 9;
        const int a   = ba - 9 * b;
        const int hw0 = hwq << 2;

        const int ctbase = (b * plane + hw0) * 9 + a;
        const int c0 = ct[ctbase], c1 = ct[ctbase + 9], c2 = ct[ctbase + 18], c3 = ct[ctbase + 27];
        const float a25x = (c0 != -2) ? 0.25f : 0.f, a75x = (c0 != -2) ? 0.75f : 0.f;
        const float a25y = (c1 != -2) ? 0.25f : 0.f, a75y = (c1 != -2) ? 0.75f : 0.f;
        const float a25z = (c2 != -2) ? 0.25f : 0.f, a75z = (c2 != -2) ? 0.75f : 0.f;
        const float a25w = (c3 != -2) ? 0.25f : 0.f, a75w = (c3 != -2) ? 0.75f : 0.f;

        const int k0 = s * KPER;
        const float* cptr = co + (b * 810 + a * 90 + k0) * plane + hw0;

        #pragma unroll 5
        for (int kk = 0; kk < KPER; ++kk) {
            const int k = k0 + kk;
            const float4 v = *reinterpret_cast<const float4*>(cptr);
            cptr += plane;
            ax_ += focal3(v.x, c0 == k, a25x, a75x);
            ay_ += focal3(v.y, c1 == k, a25y, a75y);
            az_ += focal3(v.z, c2 == k, a25z, a75z);
            aw_ += focal3(v.w, c3 == k, a25w, a75w);
        }
    }

    __shared__ float sred[4];
    const float r = block_reduce((ax_ + ay_) + (az_ + aw_), sred);
    if (threadIdx.x == 0) partial[blockIdx.x] = r;
}

__global__ __launch_bounds__(256) void box_kernel(BoxPtrs P, const float* __restrict__ anchors,
                                                 float* bpart, float* mpart) {
    const int tid = blockIdx.x * blockDim.x + threadIdx.x;
    const int nth = gridDim.x * blockDim.x;
    float accL = 0.f, accM = 0.f;

    for (int idx = tid; idx < BN; idx += nth) {
        const int b = idx / NANCH;
        const int n = idx - b * NANCH;
        const float* bo; const float* bt; int lw, nl;
        if (n < 36864)      { bo = P.bo[0]; bt = P.bt[0]; lw = 6; nl = n; }
        else if (n < 46080) { bo = P.bo[1]; bt = P.bt[1]; lw = 5; nl = n - 36864; }
        else if (n < 48384) { bo = P.bo[2]; bt = P.bt[2]; lw = 4; nl = n - 46080; }
        else if (n < 48960) { bo = P.bo[3]; bt = P.bt[3]; lw = 3; nl = n - 48384; }
        else                { bo = P.bo[4]; bt = P.bt[4]; lw = 2; nl = n - 48960; }
        const int a  = nl % 9;
        const int hw = nl / 9;
        const int plane = 1 << (2 * lw);

        const float4 r = *reinterpret_cast<const float4*>(bt + (((b * plane + hw) * 9 + a) << 2));
        if (r.x != 0.f && r.y != 0.f && r.z != 0.f && r.w != 0.f) {
            accM += 1.f;
            const float* base = bo + (b * 36 + a * 4) * plane + hw;
            const float o0 = base[0], o1 = base[plane], o2 = base[2 * plane], o3 = base[3 * plane];
            const float4 an = *reinterpret_cast<const float4*>(anchors + 4 * n);
            const float ha = an.z - an.x, wa = an.w - an.y;
            const float yca = (an.x + an.z) * 0.5f, xca = (an.y + an.w) * 0.5f;
            const float th_ = __builtin_amdgcn_exp2f(LOG2E * r.z) * ha;
            const float tw_ = __builtin_amdgcn_exp2f(LOG2E * r.w) * wa;
            const float tyc = r.x * ha + yca,  txc = r.y * wa + xca;
            const float ty1 = tyc - th_ * 0.5f, tx1 = txc - tw_ * 0.5f;
            const float ty2 = tyc + th_ * 0.5f, tx2 = txc + tw_ * 0.5f;
            const float oh_ = __builtin_amdgcn_exp2f(LOG2E * o2) * ha;
            const float ow_ = __builtin_amdgcn_exp2f(LOG2E * o3) * wa;
            const float oyc = o0 * ha + yca,  oxc = o1 * wa + xca;
            const float oy1 = oyc - oh_ * 0.5f, ox1 = oxc - ow_ * 0.5f;
            const float oy2 = oyc + oh_ * 0.5f, ox2 = oxc + ow_ * 0.5f;

            const float Ag = (tx2 - tx1) * (ty2 - ty1);
            const float Ap = (ox2 - ox1) * (oy2 - oy1);
            const float yi1 = fmaxf(ty1, oy1), xi1 = fmaxf(tx1, ox1);
            const float yi2 = fminf(ty2, oy2), xi2 = fminf(tx2, ox2);
            const float I  = (xi2 > xi1 && yi2 > yi1) ? (xi2 - xi1) * (yi2 - yi1) : 0.f;
            const float U  = Ap + Ag - I;
            const float iou = I / (U + 1e-7f);
            const float yo1 = fminf(ty1, oy1), xo1 = fminf(tx1, ox1);
            const float yo2 = fmaxf(ty2, oy2), xo2 = fmaxf(tx2, ox2);
            const float Ac = (xo2 - xo1) * (yo2 - yo1);
            const float pen = (Ac - U) / (Ac + 1e-7f);
            accL += 1.f - iou + pen;
        }
    }

    __shared__ float sred[4];
    const float rl = block_reduce(accL, sred);
    if (threadIdx.x == 0) bpart[blockIdx.x] = rl;
    __syncthreads();
    const float rm = block_reduce(accM, sred);
    if (threadIdx.x == 0) mpart[blockIdx.x] = rm;
}

__global__ __launch_bounds__(256) void finalize_kernel(const float* __restrict__ ws,
                                                       const float* __restrict__ npos,
                                                       float* __restrict__ out) {
    float c = 0.f, bx = 0.f, mk = 0.f;
    for (int i = threadIdx.x; i < CLS_GRID; i += 256) c += ws[i];
    for (int i = threadIdx.x; i < BOX_GRID; i += 256) {
        bx += ws[CLS_GRID + i];
        mk += ws[CLS_GRID + BOX_GRID + i];
    }
    __shared__ float sred[4];
    const float C  = block_reduce(c,  sred);
    __syncthreads();
    const float Bx = block_reduce(bx, sred);
    __syncthreads();
    const float Mk = block_reduce(mk, sred);
    if (threadIdx.x == 0) {
        float nps = 1.f;
        #pragma unroll
        for (int i = 0; i < 8; ++i) nps += npos[i];
        const float cls = C / nps;
        const float box = Bx / Mk;
        out[0] = cls + 50.f * box;
        out[1] = cls;
        out[2] = box;
    }
}

extern "C" void kernel_launch(void* const* d_in, const int* in_sizes, int n_in,
                              void* d_out, int out_size, void* d_ws, size_t ws_size,
                              hipStream_t stream) {
    ClsPtrs cp; BoxPtrs bp;
    for (int i = 0; i < 5; ++i) {
        cp.co[i] = (const float*)d_in[i * 4 + 0];
        bp.bo[i] = (const float*)d_in[i * 4 + 1];
        cp.ct[i] = (const int*)  d_in[i * 4 + 2];
        bp.bt[i] = (const float*)d_in[i * 4 + 3];
    }
    const float* npos    = (const float*)d_in[20];
    const float* anchors = (const float*)d_in[21];
    float* ws = (float*)d_ws;

    cls_kernel<<<CLS_GRID, 256, 0, stream>>>(cp, ws);
    box_kernel<<<BOX_GRID, 256, 0, stream>>>(bp, anchors, ws + CLS_GRID, ws + CLS_GRID + BOX_GRID);
    finalize_kernel<<<1, 256, 0, stream>>>(ws, npos, (float*)d_out);
}